// Round 18
// baseline (737.605 us; speedup 1.0000x reference)
//
#include <hip/hip_runtime.h>
#include <math.h>

#define KNOTS 8
#define HIDN 32
#define TT 4096
#define CC 512
#define NB 32
#define BOUNDF 5.0f
#define CT 32            // channels per block (8 waves x 4ch)
#define NLD 64           // f32x4 loads per lane: t = ln + 64k
#define NPAIR 128        // bf16 pairs held in regs

typedef float f32x4 __attribute__((ext_vector_type(4)));

// BARRIER-FREE wave-autonomous kernel. Wave w owns channels c0+4w..+3 for ALL T;
// lane ln covers t-rows ln+64k via dwordx4 (4ch x 1t). Moment reduction is
// intra-wave __shfl_xor (no __syncthreads anywhere) -> waves de-phase freely:
// one wave's P2 (VALU+NT stores) overlaps siblings' P1 (loads) on the same SIMD.
// Finalize: each 16-lane group computes one channel's MLP redundantly; lane
// (ln&15)==0 writes knots+bins to the WAVE-PRIVATE LDS region (same-wave
// visibility via lgkmcnt(0), no cross-wave sharing).
__global__ __launch_bounds__(512, 2)
void k_fused(const float* __restrict__ x, const float* __restrict__ W1,
             const float* __restrict__ b1, const float* __restrict__ W2,
             const float* __restrict__ b2, float* __restrict__ out)
{
    const int bb = blockIdx.y;               // 0..31
    const int w  = threadIdx.x >> 6;         // wave 0..7
    const int ln = threadIdx.x & 63;         // lane = t-row offset
    const int c0 = blockIdx.x * CT + 4 * w;  // wave's 4 channels

    __shared__ float tbl[8][4][KNOTS][8];    // per wave/ch/bin: zx,invw,kyl,h,d0,d01,-,-
    __shared__ float kn[8][4][12];           // per wave/ch: a,b,kx1..7

    const size_t base = (size_t)bb * TT * CC + c0 + (size_t)ln * CC;
    const f32x4* pxt = (const f32x4*)(x + base);
    const size_t stride4 = (size_t)64 * CC / 4;   // 64 t-rows, in f32x4 units

    // ---- Phase 1: read once (dwordx4), per-channel moments, bf16 hold ----
    unsigned int xp[NPAIR];
    float s1[4] = {0,0,0,0}, s2[4] = {0,0,0,0}, s3[4] = {0,0,0,0}, s4[4] = {0,0,0,0};
    #pragma unroll
    for (int k = 0; k < NLD; ++k) {
        const f32x4 v = pxt[(size_t)k * stride4];
        #pragma unroll
        for (int q = 0; q < 4; ++q) {
            const float vv = v[q];
            const float v2 = vv * vv;
            s1[q] += vv;
            s2[q] = fmaf(vv, vv, s2[q]);
            s3[q] = fmaf(v2, vv, s3[q]);
            s4[q] = fmaf(v2, v2, s4[q]);
        }
        unsigned int pk0, pk1;
        asm("v_cvt_pk_bf16_f32 %0, %1, %2" : "=v"(pk0) : "v"(v[0]), "v"(v[1]));
        asm("v_cvt_pk_bf16_f32 %0, %1, %2" : "=v"(pk1) : "v"(v[2]), "v"(v[3]));
        xp[2*k]   = pk0;
        xp[2*k+1] = pk1;
    }

    // ---- Intra-wave butterfly reduction: all lanes end with all 16 totals ----
    #pragma unroll
    for (int m = 1; m < 64; m <<= 1) {
        #pragma unroll
        for (int q = 0; q < 4; ++q) {
            s1[q] += __shfl_xor(s1[q], m, 64);
            s2[q] += __shfl_xor(s2[q], m, 64);
            s3[q] += __shfl_xor(s3[q], m, 64);
            s4[q] += __shfl_xor(s4[q], m, 64);
        }
    }

    // ---- Finalize: 16-lane group g computes channel q=g (redundant in group) ----
    {
        const int q = ln >> 4;
        const float t1 = (q & 2) ? ((q & 1) ? s1[3] : s1[2]) : ((q & 1) ? s1[1] : s1[0]);
        const float t2 = (q & 2) ? ((q & 1) ? s2[3] : s2[2]) : ((q & 1) ? s2[1] : s2[0]);
        const float t3 = (q & 2) ? ((q & 1) ? s3[3] : s3[2]) : ((q & 1) ? s3[1] : s3[0]);
        const float t4 = (q & 2) ? ((q & 1) ? s4[3] : s4[2]) : ((q & 1) ? s4[1] : s4[0]);

        const float n  = (float)TT;
        const float mu  = t1 / n;
        const float ex2 = t2 / n, ex3 = t3 / n, ex4 = t4 / n;
        float var = (t2 - n * mu * mu) / (n - 1.f);
        var = fmaxf(var, 0.f);
        const float sig  = fmaxf(sqrtf(var), 1e-4f);
        const float inv  = 1.f / sig;
        const float mu2  = mu * mu;
        const float ez3  = ex3 - 3.f * mu * ex2 + 2.f * mu * mu2;
        const float ez4  = ex4 - 4.f * mu * ex3 + 6.f * mu2 * ex2 - 3.f * mu2 * mu2;
        const float inv2 = inv * inv;
        const float skew  = ez3 * inv2 * inv;
        const float ekurt = ez4 * inv2 * inv2 - 3.f;

        float hid[HIDN];
        #pragma unroll
        for (int h = 0; h < HIDN; ++h) {
            float v = fmaf(W1[2*h], skew, fmaf(W1[2*h+1], ekurt, b1[h]));
            hid[h] = fmaxf(v, 0.f);
        }

        float e[KNOTS], kxr[KNOTS+1], kyr[KNOTS+1], dr[KNOTS+1];
        {   // widths -> kx
            float mx = -1e30f;
            #pragma unroll
            for (int o = 0; o < KNOTS; ++o) {
                float acc = b2[o];
                #pragma unroll
                for (int h = 0; h < HIDN; ++h) acc = fmaf(W2[o*HIDN + h], hid[h], acc);
                e[o] = acc; mx = fmaxf(mx, acc);
            }
            float sum = 0.f;
            #pragma unroll
            for (int o = 0; o < KNOTS; ++o) { e[o] = expf(e[o] - mx); sum += e[o]; }
            const float scale = (2.f * BOUNDF) / sum;
            float cum = -BOUNDF; kxr[0] = -BOUNDF;
            #pragma unroll
            for (int o = 0; o < KNOTS; ++o) { cum = fmaf(e[o], scale, cum); kxr[o+1] = cum; }
        }
        {   // heights -> ky
            float mx = -1e30f;
            #pragma unroll
            for (int o = 0; o < KNOTS; ++o) {
                float acc = b2[KNOTS + o];
                #pragma unroll
                for (int h = 0; h < HIDN; ++h) acc = fmaf(W2[(KNOTS+o)*HIDN + h], hid[h], acc);
                e[o] = acc; mx = fmaxf(mx, acc);
            }
            float sum = 0.f;
            #pragma unroll
            for (int o = 0; o < KNOTS; ++o) { e[o] = expf(e[o] - mx); sum += e[o]; }
            const float scale = (2.f * BOUNDF) / sum;
            float cum = -BOUNDF; kyr[0] = -BOUNDF;
            #pragma unroll
            for (int o = 0; o < KNOTS; ++o) { cum = fmaf(e[o], scale, cum); kyr[o+1] = cum; }
        }
        #pragma unroll
        for (int o = 0; o < KNOTS+1; ++o) {  // derivs = softplus + 1e-3
            float acc = b2[2*KNOTS + o];
            #pragma unroll
            for (int h = 0; h < HIDN; ++h) acc = fmaf(W2[(2*KNOTS+o)*HIDN + h], hid[h], acc);
            float sp = fmaxf(acc, 0.f) + log1pf(expf(-fabsf(acc)));
            dr[o] = sp + 1e-3f;
        }

        if ((ln & 15) == 0) {   // one writer lane per channel, wave-private region
            kn[w][q][0] = inv;
            kn[w][q][1] = -mu * inv;
            #pragma unroll
            for (int j = 1; j <= 7; ++j) kn[w][q][1 + j] = kxr[j];
            #pragma unroll
            for (int j = 0; j < KNOTS; ++j) {
                const float w_   = kxr[j+1] - kxr[j];
                const float wm   = fmaxf(w_, 1e-8f);
                const float invw = 1.f / wm;
                const float h    = kyr[j+1] - kyr[j];
                tbl[w][q][j][0] = -kxr[j] * invw;
                tbl[w][q][j][1] = invw;
                tbl[w][q][j][2] = kyr[j];
                tbl[w][q][j][3] = h;
                tbl[w][q][j][4] = dr[j];
                tbl[w][q][j][5] = dr[j] + dr[j+1];
            }
        }
    }
    asm volatile("s_waitcnt lgkmcnt(0)" ::: "memory");   // same-wave LDS visibility

    // ---- Load per-wave params (broadcast reads) ----
    float aq[4], bq[4], kx[4][7];
    #pragma unroll
    for (int q = 0; q < 4; ++q) {
        aq[q] = kn[w][q][0];
        bq[q] = kn[w][q][1];
        #pragma unroll
        for (int j = 0; j < 7; ++j) kx[q][j] = kn[w][q][2 + j];
    }

    // ---- Phase 2: unpack regs, 4 channel chains, dwordx4 NT store ----
    f32x4* pot = (f32x4*)(out + base);
    #pragma unroll
    for (int k = 0; k < NLD; ++k) {
        const unsigned int u0 = xp[2*k], u1 = xp[2*k+1];
        float xv[4];
        xv[0] = __uint_as_float(u0 << 16);
        xv[1] = __uint_as_float(u0 & 0xffff0000u);
        xv[2] = __uint_as_float(u1 << 16);
        xv[3] = __uint_as_float(u1 & 0xffff0000u);
        f32x4 r;
        #pragma unroll
        for (int q = 0; q < 4; ++q) {
            const float z = fmaf(xv[q], aq[q], bq[q]);
            const bool  c4 = z >= kx[q][3];
            const float mB = c4 ? kx[q][5] : kx[q][1];
            const bool  cB = z >= mB;
            const float nLo = c4 ? kx[q][4] : kx[q][0];
            const float nHi = c4 ? kx[q][6] : kx[q][2];
            const float mC = cB ? nHi : nLo;
            const bool  cC = z >= mC;
            const int idx = (c4 ? 4 : 0) + (cB ? 2 : 0) + (cC ? 1 : 0);

            const float4 A = *(const float4*)&tbl[w][q][idx][0];  // zx,invw,kyl,h
            const float2 D = *(const float2*)&tbl[w][q][idx][4];  // d0,d0+d1

            const float zeta = fmaf(z, A.y, A.x);
            const float uu   = fmaf(-zeta, zeta, zeta);      // zeta*(1-zeta)
            const float s    = A.w * A.y;                    // h * invw
            const float R    = fmaf(-2.f, s, D.y);           // d0+d1-2s
            const float den  = fmaf(R, uu, s);
            const float inner= fmaf(s * zeta, zeta, D.x * uu);
            const float res  = fmaf(A.w * inner,
                                    __builtin_amdgcn_rcpf(fmaxf(den, 1e-8f)), A.z);
            r[q] = (fabsf(z) > BOUNDF) ? z : res;
        }
        __builtin_nontemporal_store(r, &pot[(size_t)k * stride4]);
    }
}

extern "C" void kernel_launch(void* const* d_in, const int* in_sizes, int n_in,
                              void* d_out, int out_size, void* d_ws, size_t ws_size,
                              hipStream_t stream) {
    const float* x  = (const float*)d_in[0];
    const float* W1 = (const float*)d_in[1];
    const float* b1 = (const float*)d_in[2];
    const float* W2 = (const float*)d_in[3];
    const float* b2 = (const float*)d_in[4];
    float* out = (float*)d_out;

    k_fused<<<dim3(CC / CT, NB), dim3(512), 0, stream>>>(x, W1, b1, W2, b2, out);
}

// Round 19
// 155.986 us; speedup vs baseline: 4.7287x; 4.7287x over previous
//
#include <hip/hip_runtime.h>
#include <math.h>

#define KNOTS 8
#define HIDN 32
#define TT 4096
#define CC 512
#define NB 32
#define BOUNDF 5.0f

// ws param tile layout (floats), tile = bb*16 + ctile (32 channels each):
//   [0..31]       a = 1/sigma
//   [32..63]      b = -mu/sigma
//   [64..287]     kx[7][32]
//   [288..1343]   bZ float2[8][33]  (-kxl*invw, invw)   33-pad: bank = 2j+2c
//   [1344..2399]  bY float2[8][33]  (kyl, h)
//   [2400..3455]  bD float2[8][33]  (d0, d0+d1)
#define BZOFF 288
#define BYOFF 1344
#define BDOFF 2400
#define TILEF 3456

typedef float f32x4 __attribute__((ext_vector_type(4)));

// ---------- Kernel 1: moments + MLP -> param tiles in ws (NO value hold) ----------
__global__ __launch_bounds__(1024, 4)
void k_stats(const float* __restrict__ x, const float* __restrict__ W1,
             const float* __restrict__ b1, const float* __restrict__ W2,
             const float* __restrict__ b2, float* __restrict__ ws)
{
    const int bb = blockIdx.y;
    const int ctile = blockIdx.x;
    const int c0 = ctile * 32;
    const int lc = threadIdx.x & 7;          // channel quad 4lc..4lc+3
    const int tg = threadIdx.x >> 3;         // 0..127 t-row
    const int w  = threadIdx.x >> 6;         // wave 0..15
    const int ln = threadIdx.x & 63;

    __shared__ float red4[16][4][32];
    __shared__ float mom[4][32];

    const f32x4* pxt = (const f32x4*)(x + (size_t)bb * TT * CC + c0 + 4 * lc
                                        + (size_t)tg * CC);
    const size_t stride4 = (size_t)128 * CC / 4;

    float s1[4] = {0,0,0,0}, s2[4] = {0,0,0,0}, s3[4] = {0,0,0,0}, s4[4] = {0,0,0,0};
    #pragma unroll
    for (int k = 0; k < 32; ++k) {           // t = tg + 128k
        const f32x4 v = pxt[(size_t)k * stride4];
        #pragma unroll
        for (int q = 0; q < 4; ++q) {
            const float vv = v[q], v2 = vv * vv;
            s1[q] += vv;
            s2[q] = fmaf(vv, vv, s2[q]);
            s3[q] = fmaf(v2, vv, s3[q]);
            s4[q] = fmaf(v2, v2, s4[q]);
        }
    }
    // in-wave reduce over the 8 row-groups (lane bits 3..5)
    #pragma unroll
    for (int m = 8; m < 64; m <<= 1) {
        #pragma unroll
        for (int q = 0; q < 4; ++q) {
            s1[q] += __shfl_xor(s1[q], m, 64);
            s2[q] += __shfl_xor(s2[q], m, 64);
            s3[q] += __shfl_xor(s3[q], m, 64);
            s4[q] += __shfl_xor(s4[q], m, 64);
        }
    }
    if (ln < 8) {
        #pragma unroll
        for (int q = 0; q < 4; ++q) {
            red4[w][0][4*ln+q] = s1[q];
            red4[w][1][4*ln+q] = s2[q];
            red4[w][2][4*ln+q] = s3[q];
            red4[w][3][4*ln+q] = s4[q];
        }
    }
    __syncthreads();

    if (threadIdx.x < 128) {
        const int m = threadIdx.x >> 5, c = threadIdx.x & 31;
        float acc = 0.f;
        #pragma unroll
        for (int g = 0; g < 16; ++g) acc += red4[g][m][c];
        mom[m][c] = acc;
    }
    __syncthreads();

    if (threadIdx.x < 32) {
        const int c = threadIdx.x;
        const float n  = (float)TT;
        const float t1 = mom[0][c], t2 = mom[1][c], t3 = mom[2][c], t4 = mom[3][c];
        const float mu  = t1 / n;
        const float ex2 = t2 / n, ex3 = t3 / n, ex4 = t4 / n;
        float var = (t2 - n * mu * mu) / (n - 1.f);
        var = fmaxf(var, 0.f);
        const float sig  = fmaxf(sqrtf(var), 1e-4f);
        const float inv  = 1.f / sig;
        const float mu2  = mu * mu;
        const float ez3  = ex3 - 3.f * mu * ex2 + 2.f * mu * mu2;
        const float ez4  = ex4 - 4.f * mu * ex3 + 6.f * mu2 * ex2 - 3.f * mu2 * mu2;
        const float inv2 = inv * inv;
        const float skew  = ez3 * inv2 * inv;
        const float ekurt = ez4 * inv2 * inv2 - 3.f;

        float hid[HIDN];
        #pragma unroll
        for (int h = 0; h < HIDN; ++h) {
            float v = fmaf(W1[2*h], skew, fmaf(W1[2*h+1], ekurt, b1[h]));
            hid[h] = fmaxf(v, 0.f);
        }

        float e[KNOTS], kxr[KNOTS+1], kyr[KNOTS+1], dr[KNOTS+1];
        {   // widths -> kx
            float mx = -1e30f;
            #pragma unroll
            for (int o = 0; o < KNOTS; ++o) {
                float acc = b2[o];
                #pragma unroll
                for (int h = 0; h < HIDN; ++h) acc = fmaf(W2[o*HIDN + h], hid[h], acc);
                e[o] = acc; mx = fmaxf(mx, acc);
            }
            float sum = 0.f;
            #pragma unroll
            for (int o = 0; o < KNOTS; ++o) { e[o] = expf(e[o] - mx); sum += e[o]; }
            const float scale = (2.f * BOUNDF) / sum;
            float cum = -BOUNDF; kxr[0] = -BOUNDF;
            #pragma unroll
            for (int o = 0; o < KNOTS; ++o) { cum = fmaf(e[o], scale, cum); kxr[o+1] = cum; }
        }
        {   // heights -> ky
            float mx = -1e30f;
            #pragma unroll
            for (int o = 0; o < KNOTS; ++o) {
                float acc = b2[KNOTS + o];
                #pragma unroll
                for (int h = 0; h < HIDN; ++h) acc = fmaf(W2[(KNOTS+o)*HIDN + h], hid[h], acc);
                e[o] = acc; mx = fmaxf(mx, acc);
            }
            float sum = 0.f;
            #pragma unroll
            for (int o = 0; o < KNOTS; ++o) { e[o] = expf(e[o] - mx); sum += e[o]; }
            const float scale = (2.f * BOUNDF) / sum;
            float cum = -BOUNDF; kyr[0] = -BOUNDF;
            #pragma unroll
            for (int o = 0; o < KNOTS; ++o) { cum = fmaf(e[o], scale, cum); kyr[o+1] = cum; }
        }
        #pragma unroll
        for (int o = 0; o < KNOTS+1; ++o) {
            float acc = b2[2*KNOTS + o];
            #pragma unroll
            for (int h = 0; h < HIDN; ++h) acc = fmaf(W2[(2*KNOTS+o)*HIDN + h], hid[h], acc);
            float sp = fmaxf(acc, 0.f) + log1pf(expf(-fabsf(acc)));
            dr[o] = sp + 1e-3f;
        }

        float* tb = ws + (size_t)(bb * 16 + ctile) * TILEF;
        tb[c]      = inv;
        tb[32 + c] = -mu * inv;
        #pragma unroll
        for (int j = 1; j <= 7; ++j) tb[64 + (j-1)*32 + c] = kxr[j];
        float2* bz = (float2*)(tb + BZOFF);
        float2* by = (float2*)(tb + BYOFF);
        float2* bd = (float2*)(tb + BDOFF);
        #pragma unroll
        for (int j = 0; j < KNOTS; ++j) {
            const float wd   = kxr[j+1] - kxr[j];
            const float wm   = fmaxf(wd, 1e-8f);
            const float invw = 1.f / wm;
            const float h    = kyr[j+1] - kyr[j];
            bz[j*33 + c] = make_float2(-kxr[j] * invw, invw);
            by[j*33 + c] = make_float2(kyr[j], h);
            bd[j*33 + c] = make_float2(dr[j], dr[j] + dr[j+1]);
        }
    }
}

// ---------- Kernel 2: apply spline (x re-read is L3-hot; high occupancy) ----------
__global__ __launch_bounds__(256, 6)
void k_apply(const float* __restrict__ x, const float* __restrict__ ws,
             float* __restrict__ out)
{
    const int tch   = blockIdx.x;   // 0..7  (512 t-rows)
    const int ctile = blockIdx.y;   // 0..15
    const int bb    = blockIdx.z;   // 0..31
    const int c0 = ctile * 32;
    const int lc = threadIdx.x & 7;          // channel quad
    const int tg = threadIdx.x >> 3;         // 0..31

    __shared__ float sp[TILEF];
    {
        const f32x4* src = (const f32x4*)(ws + (size_t)(bb * 16 + ctile) * TILEF);
        f32x4* dst = (f32x4*)sp;
        for (int i = threadIdx.x; i < TILEF / 4; i += 256) dst[i] = src[i];
    }
    __syncthreads();

    float aq[4], bq[4], kx[4][7];
    #pragma unroll
    for (int q = 0; q < 4; ++q) {
        const int c = 4*lc + q;
        aq[q] = sp[c];
        bq[q] = sp[32 + c];
        #pragma unroll
        for (int j = 0; j < 7; ++j) kx[q][j] = sp[64 + j*32 + c];
    }
    const float2* bz = (const float2*)(sp + BZOFF);
    const float2* by = (const float2*)(sp + BYOFF);
    const float2* bd = (const float2*)(sp + BDOFF);

    const size_t base = (size_t)bb * TT * CC + (size_t)(tch * 512 + tg) * CC
                        + c0 + 4 * lc;
    const f32x4* pxt = (const f32x4*)(x + base);
    f32x4*       pot = (f32x4*)(out + base);
    const size_t stride4 = (size_t)32 * CC / 4;

    #pragma unroll 4
    for (int k = 0; k < 16; ++k) {           // t = tch*512 + tg + 32k
        const f32x4 v = pxt[(size_t)k * stride4];
        f32x4 r;
        #pragma unroll
        for (int q = 0; q < 4; ++q) {
            const float z = fmaf(v[q], aq[q], bq[q]);
            const bool  c4 = z >= kx[q][3];
            const float mB = c4 ? kx[q][5] : kx[q][1];
            const bool  cB = z >= mB;
            const float nLo = c4 ? kx[q][4] : kx[q][0];
            const float nHi = c4 ? kx[q][6] : kx[q][2];
            const float mC = cB ? nHi : nLo;
            const bool  cC = z >= mC;
            const int idx = (c4 ? 4 : 0) + (cB ? 2 : 0) + (cC ? 1 : 0);
            const int off = idx * 33 + 4*lc + q;

            const float2 Z = bz[off];
            const float2 Y = by[off];
            const float2 D = bd[off];

            const float zeta = fmaf(z, Z.y, Z.x);
            const float uu   = fmaf(-zeta, zeta, zeta);
            const float s    = Y.y * Z.y;
            const float R    = fmaf(-2.f, s, D.y);
            const float den  = fmaf(R, uu, s);
            const float inner= fmaf(s * zeta, zeta, D.x * uu);
            const float res  = fmaf(Y.y * inner,
                                    __builtin_amdgcn_rcpf(fmaxf(den, 1e-8f)), Y.x);
            r[q] = (fabsf(z) > BOUNDF) ? z : res;
        }
        __builtin_nontemporal_store(r, &pot[(size_t)k * stride4]);
    }
}

extern "C" void kernel_launch(void* const* d_in, const int* in_sizes, int n_in,
                              void* d_out, int out_size, void* d_ws, size_t ws_size,
                              hipStream_t stream) {
    const float* x  = (const float*)d_in[0];
    const float* W1 = (const float*)d_in[1];
    const float* b1 = (const float*)d_in[2];
    const float* W2 = (const float*)d_in[3];
    const float* b2 = (const float*)d_in[4];
    float* out = (float*)d_out;
    float* ws  = (float*)d_ws;

    k_stats<<<dim3(16, NB), dim3(1024), 0, stream>>>(x, W1, b1, W2, b2, ws);
    k_apply<<<dim3(8, 16, NB), dim3(256), 0, stream>>>(x, ws, out);
}

// Round 20
// 121.479 us; speedup vs baseline: 6.0719x; 1.2841x over previous
//
#include <hip/hip_runtime.h>
#include <math.h>

#define KNOTS 8
#define HIDN 32
#define TT 4096
#define CC 512
#define NB 32
#define BOUNDF 5.0f
#define NLD 64           // k-steps per slice (t = tg + 64k)
#define TPAD 33          // padded float2 row for bin tables

typedef float f32x4 __attribute__((ext_vector_type(4)));

__device__ __forceinline__ void finalize_ch(
    int c, float t1, float t2, float t3, float t4,
    const float* __restrict__ W1, const float* __restrict__ b1,
    const float* __restrict__ W2, const float* __restrict__ b2,
    float* pA, float* pB, float* pKx /* [7][32] */,
    float2* bz, float2* by, float2* bd /* [KNOTS*TPAD] */)
{
    const float n  = (float)TT;
    const float mu  = t1 / n;
    const float ex2 = t2 / n, ex3 = t3 / n, ex4 = t4 / n;
    float var = (t2 - n * mu * mu) / (n - 1.f);
    var = fmaxf(var, 0.f);
    const float sig  = fmaxf(sqrtf(var), 1e-4f);
    const float inv  = 1.f / sig;
    const float mu2  = mu * mu;
    const float ez3  = ex3 - 3.f * mu * ex2 + 2.f * mu * mu2;
    const float ez4  = ex4 - 4.f * mu * ex3 + 6.f * mu2 * ex2 - 3.f * mu2 * mu2;
    const float inv2 = inv * inv;
    const float skew  = ez3 * inv2 * inv;
    const float ekurt = ez4 * inv2 * inv2 - 3.f;

    float hid[HIDN];
    #pragma unroll
    for (int h = 0; h < HIDN; ++h) {
        float v = fmaf(W1[2*h], skew, fmaf(W1[2*h+1], ekurt, b1[h]));
        hid[h] = fmaxf(v, 0.f);
    }

    float e[KNOTS], kxr[KNOTS+1], kyr[KNOTS+1], dr[KNOTS+1];
    {   // widths -> kx
        float mx = -1e30f;
        #pragma unroll
        for (int o = 0; o < KNOTS; ++o) {
            float acc = b2[o];
            #pragma unroll
            for (int h = 0; h < HIDN; ++h) acc = fmaf(W2[o*HIDN + h], hid[h], acc);
            e[o] = acc; mx = fmaxf(mx, acc);
        }
        float sum = 0.f;
        #pragma unroll
        for (int o = 0; o < KNOTS; ++o) { e[o] = expf(e[o] - mx); sum += e[o]; }
        const float scale = (2.f * BOUNDF) / sum;
        float cum = -BOUNDF; kxr[0] = -BOUNDF;
        #pragma unroll
        for (int o = 0; o < KNOTS; ++o) { cum = fmaf(e[o], scale, cum); kxr[o+1] = cum; }
    }
    {   // heights -> ky
        float mx = -1e30f;
        #pragma unroll
        for (int o = 0; o < KNOTS; ++o) {
            float acc = b2[KNOTS + o];
            #pragma unroll
            for (int h = 0; h < HIDN; ++h) acc = fmaf(W2[(KNOTS+o)*HIDN + h], hid[h], acc);
            e[o] = acc; mx = fmaxf(mx, acc);
        }
        float sum = 0.f;
        #pragma unroll
        for (int o = 0; o < KNOTS; ++o) { e[o] = expf(e[o] - mx); sum += e[o]; }
        const float scale = (2.f * BOUNDF) / sum;
        float cum = -BOUNDF; kyr[0] = -BOUNDF;
        #pragma unroll
        for (int o = 0; o < KNOTS; ++o) { cum = fmaf(e[o], scale, cum); kyr[o+1] = cum; }
    }
    #pragma unroll
    for (int o = 0; o < KNOTS+1; ++o) {   // derivs = softplus + 1e-3
        float acc = b2[2*KNOTS + o];
        #pragma unroll
        for (int h = 0; h < HIDN; ++h) acc = fmaf(W2[(2*KNOTS+o)*HIDN + h], hid[h], acc);
        float sp = fmaxf(acc, 0.f) + log1pf(expf(-fabsf(acc)));
        dr[o] = sp + 1e-3f;
    }

    pA[c] = inv;
    pB[c] = -mu * inv;
    #pragma unroll
    for (int j = 1; j <= 7; ++j) pKx[(j-1)*32 + c] = kxr[j];
    #pragma unroll
    for (int j = 0; j < KNOTS; ++j) {
        const float wd   = kxr[j+1] - kxr[j];
        const float wm   = fmaxf(wd, 1e-8f);
        const float invw = 1.f / wm;
        const float h    = kyr[j+1] - kyr[j];
        bz[j*TPAD + c] = make_float2(-kxr[j] * invw, invw);
        by[j*TPAD + c] = make_float2(kyr[j], h);
        bd[j*TPAD + c] = make_float2(dr[j], dr[j] + dr[j+1]);
    }
}

// Persistent pipelined block: grid 256 (1/CU), 512 thr = 8 waves.
// Each block owns TWO adjacent 32-ch slices of one batch row.
// A: P1(s0) -> hold xp. B: middle loop -- per k: spline+NT-store s0's pair
//    (frees xp[2k],xp[2k+1]) then load s1's k-chunk into the SAME regs,
//    accumulating s1 moments => loads AND stores in flight together (the
//    convoy-breaker). C: finalize(s1), drain P2(s1).
__global__ __launch_bounds__(512, 2)
void k_fused(const float* __restrict__ x, const float* __restrict__ W1,
             const float* __restrict__ b1, const float* __restrict__ W2,
             const float* __restrict__ b2, float* __restrict__ out)
{
    const int bb = blockIdx.y;               // 0..31
    const int jj = blockIdx.x;               // 0..7 (slice pair)
    const int c0a = jj * 64;                 // slice0 channels
    const int lc = threadIdx.x & 7;          // c-quad lane
    const int tg = threadIdx.x >> 3;         // 0..63 t-row
    const int w  = threadIdx.x >> 6;         // wave 0..7
    const int ln = threadIdx.x & 63;

    __shared__ float red4[8][4][32];
    __shared__ float mom[4][32];
    __shared__ float pA[2][32], pB[2][32], pKx[2][7*32];
    __shared__ float2 bzT[2][KNOTS*TPAD], byT[2][KNOTS*TPAD], bdT[2][KNOTS*TPAD];

    const size_t baseA = (size_t)bb * TT * CC + c0a + 4 * lc + (size_t)tg * CC;
    const f32x4* pxA = (const f32x4*)(x + baseA);
    const f32x4* pxB = (const f32x4*)(x + baseA + 32);
    f32x4* poA = (f32x4*)(out + baseA);
    f32x4* poB = (f32x4*)(out + baseA + 32);
    const size_t stride4 = (size_t)64 * CC / 4;

    unsigned int xp[2 * NLD];
    float s1[4] = {0,0,0,0}, s2[4] = {0,0,0,0}, s3[4] = {0,0,0,0}, s4[4] = {0,0,0,0};

    // ---- Phase A: P1(slice0) ----
    #pragma unroll
    for (int k = 0; k < NLD; ++k) {
        const f32x4 v = pxA[(size_t)k * stride4];
        #pragma unroll
        for (int q = 0; q < 4; ++q) {
            const float vv = v[q], v2 = vv * vv;
            s1[q] += vv;
            s2[q] = fmaf(vv, vv, s2[q]);
            s3[q] = fmaf(v2, vv, s3[q]);
            s4[q] = fmaf(v2, v2, s4[q]);
        }
        unsigned int pk0, pk1;
        asm("v_cvt_pk_bf16_f32 %0, %1, %2" : "=v"(pk0) : "v"(v[0]), "v"(v[1]));
        asm("v_cvt_pk_bf16_f32 %0, %1, %2" : "=v"(pk1) : "v"(v[2]), "v"(v[3]));
        xp[2*k] = pk0; xp[2*k+1] = pk1;
    }
    // in-wave reduce over lane bits 3..5 (8 row-groups)
    #pragma unroll
    for (int m = 8; m < 64; m <<= 1)
        #pragma unroll
        for (int q = 0; q < 4; ++q) {
            s1[q] += __shfl_xor(s1[q], m, 64);
            s2[q] += __shfl_xor(s2[q], m, 64);
            s3[q] += __shfl_xor(s3[q], m, 64);
            s4[q] += __shfl_xor(s4[q], m, 64);
        }
    if (ln < 8) {
        #pragma unroll
        for (int q = 0; q < 4; ++q) {
            red4[w][0][4*ln+q] = s1[q];
            red4[w][1][4*ln+q] = s2[q];
            red4[w][2][4*ln+q] = s3[q];
            red4[w][3][4*ln+q] = s4[q];
        }
    }
    __syncthreads();
    if (threadIdx.x < 128) {
        const int m = threadIdx.x >> 5, c = threadIdx.x & 31;
        float acc = 0.f;
        #pragma unroll
        for (int g = 0; g < 8; ++g) acc += red4[g][m][c];
        mom[m][c] = acc;
    }
    __syncthreads();
    if (threadIdx.x < 32)
        finalize_ch(threadIdx.x, mom[0][threadIdx.x], mom[1][threadIdx.x],
                    mom[2][threadIdx.x], mom[3][threadIdx.x],
                    W1, b1, W2, b2, pA[0], pB[0], pKx[0], bzT[0], byT[0], bdT[0]);
    __syncthreads();

    // slice0 params -> regs
    float aq[4], bq[4], kxq[4][7];
    #pragma unroll
    for (int q = 0; q < 4; ++q) {
        const int c = 4*lc + q;
        aq[q] = pA[0][c]; bq[q] = pB[0][c];
        #pragma unroll
        for (int j = 0; j < 7; ++j) kxq[q][j] = pKx[0][j*32 + c];
    }

    // ---- Phase B: middle loop -- store s0, load s1 (mixed r/w in flight) ----
    #pragma unroll
    for (int q = 0; q < 4; ++q) { s1[q]=0.f; s2[q]=0.f; s3[q]=0.f; s4[q]=0.f; }
    #pragma unroll
    for (int k = 0; k < NLD; ++k) {
        // consume + store slice0 pair k
        {
            const unsigned int u0 = xp[2*k], u1 = xp[2*k+1];
            float xv[4];
            xv[0] = __uint_as_float(u0 << 16);
            xv[1] = __uint_as_float(u0 & 0xffff0000u);
            xv[2] = __uint_as_float(u1 << 16);
            xv[3] = __uint_as_float(u1 & 0xffff0000u);
            f32x4 r;
            #pragma unroll
            for (int q = 0; q < 4; ++q) {
                const float z = fmaf(xv[q], aq[q], bq[q]);
                const bool  c4 = z >= kxq[q][3];
                const float mB = c4 ? kxq[q][5] : kxq[q][1];
                const bool  cB = z >= mB;
                const float nLo = c4 ? kxq[q][4] : kxq[q][0];
                const float nHi = c4 ? kxq[q][6] : kxq[q][2];
                const float mC = cB ? nHi : nLo;
                const bool  cC = z >= mC;
                const int idx = (c4 ? 4 : 0) + (cB ? 2 : 0) + (cC ? 1 : 0);
                const int off = idx * TPAD + 4*lc + q;
                const float2 Z = bzT[0][off];
                const float2 Y = byT[0][off];
                const float2 D = bdT[0][off];
                const float zeta = fmaf(z, Z.y, Z.x);
                const float uu   = fmaf(-zeta, zeta, zeta);
                const float s    = Y.y * Z.y;
                const float R    = fmaf(-2.f, s, D.y);
                const float den  = fmaf(R, uu, s);
                const float inner= fmaf(s * zeta, zeta, D.x * uu);
                const float res  = fmaf(Y.y * inner,
                                        __builtin_amdgcn_rcpf(fmaxf(den, 1e-8f)), Y.x);
                r[q] = (fabsf(z) > BOUNDF) ? z : res;
            }
            __builtin_nontemporal_store(r, &poA[(size_t)k * stride4]);
        }
        // load slice1 chunk k into the just-freed registers
        {
            const f32x4 v = pxB[(size_t)k * stride4];
            #pragma unroll
            for (int q = 0; q < 4; ++q) {
                const float vv = v[q], v2 = vv * vv;
                s1[q] += vv;
                s2[q] = fmaf(vv, vv, s2[q]);
                s3[q] = fmaf(v2, vv, s3[q]);
                s4[q] = fmaf(v2, v2, s4[q]);
            }
            unsigned int pk0, pk1;
            asm("v_cvt_pk_bf16_f32 %0, %1, %2" : "=v"(pk0) : "v"(v[0]), "v"(v[1]));
            asm("v_cvt_pk_bf16_f32 %0, %1, %2" : "=v"(pk1) : "v"(v[2]), "v"(v[3]));
            xp[2*k] = pk0; xp[2*k+1] = pk1;
        }
    }
    // reduce slice1 moments
    #pragma unroll
    for (int m = 8; m < 64; m <<= 1)
        #pragma unroll
        for (int q = 0; q < 4; ++q) {
            s1[q] += __shfl_xor(s1[q], m, 64);
            s2[q] += __shfl_xor(s2[q], m, 64);
            s3[q] += __shfl_xor(s3[q], m, 64);
            s4[q] += __shfl_xor(s4[q], m, 64);
        }
    if (ln < 8) {
        #pragma unroll
        for (int q = 0; q < 4; ++q) {
            red4[w][0][4*ln+q] = s1[q];
            red4[w][1][4*ln+q] = s2[q];
            red4[w][2][4*ln+q] = s3[q];
            red4[w][3][4*ln+q] = s4[q];
        }
    }
    __syncthreads();
    if (threadIdx.x < 128) {
        const int m = threadIdx.x >> 5, c = threadIdx.x & 31;
        float acc = 0.f;
        #pragma unroll
        for (int g = 0; g < 8; ++g) acc += red4[g][m][c];
        mom[m][c] = acc;
    }
    __syncthreads();
    if (threadIdx.x < 32)
        finalize_ch(threadIdx.x, mom[0][threadIdx.x], mom[1][threadIdx.x],
                    mom[2][threadIdx.x], mom[3][threadIdx.x],
                    W1, b1, W2, b2, pA[1], pB[1], pKx[1], bzT[1], byT[1], bdT[1]);
    __syncthreads();

    // slice1 params -> regs (reuse)
    #pragma unroll
    for (int q = 0; q < 4; ++q) {
        const int c = 4*lc + q;
        aq[q] = pA[1][c]; bq[q] = pB[1][c];
        #pragma unroll
        for (int j = 0; j < 7; ++j) kxq[q][j] = pKx[1][j*32 + c];
    }

    // ---- Phase C: drain P2(slice1) ----
    #pragma unroll
    for (int k = 0; k < NLD; ++k) {
        const unsigned int u0 = xp[2*k], u1 = xp[2*k+1];
        float xv[4];
        xv[0] = __uint_as_float(u0 << 16);
        xv[1] = __uint_as_float(u0 & 0xffff0000u);
        xv[2] = __uint_as_float(u1 << 16);
        xv[3] = __uint_as_float(u1 & 0xffff0000u);
        f32x4 r;
        #pragma unroll
        for (int q = 0; q < 4; ++q) {
            const float z = fmaf(xv[q], aq[q], bq[q]);
            const bool  c4 = z >= kxq[q][3];
            const float mB = c4 ? kxq[q][5] : kxq[q][1];
            const bool  cB = z >= mB;
            const float nLo = c4 ? kxq[q][4] : kxq[q][0];
            const float nHi = c4 ? kxq[q][6] : kxq[q][2];
            const float mC = cB ? nHi : nLo;
            const bool  cC = z >= mC;
            const int idx = (c4 ? 4 : 0) + (cB ? 2 : 0) + (cC ? 1 : 0);
            const int off = idx * TPAD + 4*lc + q;
            const float2 Z = bzT[1][off];
            const float2 Y = byT[1][off];
            const float2 D = bdT[1][off];
            const float zeta = fmaf(z, Z.y, Z.x);
            const float uu   = fmaf(-zeta, zeta, zeta);
            const float s    = Y.y * Z.y;
            const float R    = fmaf(-2.f, s, D.y);
            const float den  = fmaf(R, uu, s);
            const float inner= fmaf(s * zeta, zeta, D.x * uu);
            const float res  = fmaf(Y.y * inner,
                                    __builtin_amdgcn_rcpf(fmaxf(den, 1e-8f)), Y.x);
            r[q] = (fabsf(z) > BOUNDF) ? z : res;
        }
        __builtin_nontemporal_store(r, &poB[(size_t)k * stride4]);
    }
}

extern "C" void kernel_launch(void* const* d_in, const int* in_sizes, int n_in,
                              void* d_out, int out_size, void* d_ws, size_t ws_size,
                              hipStream_t stream) {
    const float* x  = (const float*)d_in[0];
    const float* W1 = (const float*)d_in[1];
    const float* b1 = (const float*)d_in[2];
    const float* W2 = (const float*)d_in[3];
    const float* b2 = (const float*)d_in[4];
    float* out = (float*)d_out;

    k_fused<<<dim3(8, NB), dim3(512), 0, stream>>>(x, W1, b1, W2, b2, out);
}